// Round 9
// baseline (421.407 us; speedup 1.0000x reference)
//
#include <hip/hip_runtime.h>
#include <cmath>
#include <type_traits>

#pragma clang fp contract(off)

#define NSAVE 101
#define NSUB  20
#define NCTRL 10
#define IV_PER_K 10   // 100 save intervals / 10 control intervals

typedef float v2f __attribute__((ext_vector_type(2)));

// Packed f32 math via LLVM vector ops -> v_pk_fma_f32 / v_pk_mul_f32 / v_pk_add_f32
// on gfx950, per-element IEEE semantics (R8-verified: bit-stable vs scalar).
__device__ __forceinline__ v2f pk_fma(v2f a, v2f b, v2f c) {
    return __builtin_elementwise_fma(a, b, c);
}

// np-faithful pow for the exponents that occur (generic fallback path only).
__device__ __forceinline__ float pow_np_f32(float x, float p) {
    if (p == 2.5f) return (x * x) * sqrtf(x);
    if (p == 1.0f) return x;
    if (p == 2.0f) return x * x;
    return powf(x, p);
}

// h-premultiplied Butcher constants (double product, rounded once)
#define HCF(x) ((float)(0.05 * (x)))
__device__ constexpr float HA21 = HCF(0.161);
__device__ constexpr float HA31 = HCF(-0.008480655492356989), HA32 = HCF(0.335480655492357);
__device__ constexpr float HA41 = HCF(2.8971530571054935),  HA42 = HCF(-6.359448489975075),  HA43 = HCF(4.3622954328695815);
__device__ constexpr float HA51 = HCF(5.325864828439257),   HA52 = HCF(-11.748883564062828), HA53 = HCF(7.4955393428898365), HA54 = HCF(-0.09249506636175525);
__device__ constexpr float HA61 = HCF(5.86145544294642),    HA62 = HCF(-12.92096931784711),  HA63 = HCF(8.159367898576159),  HA64 = HCF(-0.071584973281401), HA65 = HCF(-0.028269050394068383);
__device__ constexpr float HB1 = HCF(0.09646076681806523), HB2 = HCF(0.01), HB3 = HCF(0.4798896504144996);
__device__ constexpr float HB4 = HCF(1.379008574103742),   HB5 = HCF(-3.290069515436081), HB6 = HCF(2.324710524099774);

// Per-stage additive constants for p-coordinates (pA = 1 + zA):
// K_i = h * (row sum of A up to stage i) = h * c_i ; KY = h * sum(B) = h.
__device__ constexpr float K2 = HCF(0.161);
__device__ constexpr float K3 = HCF(0.327);
__device__ constexpr float K4 = HCF(0.9);
__device__ constexpr float K5 = HCF(0.9800255409045097);
__device__ constexpr float K6 = (float)(0.05 * (5.86145544294642 - 12.92096931784711 + 8.159367898576159 - 0.071584973281401 - 0.028269050394068383));
__device__ constexpr float KY = (float)(0.05 * (0.09646076681806523 + 0.01 + 0.4798896504144996 + 1.379008574103742 - 3.290069515436081 + 2.324710524099774));

__global__ __launch_bounds__(256, 1) void toggle_tsit5_kernel(
    const float* __restrict__ init,
    const float* __restrict__ useq,
    const float* __restrict__ params,
    float* __restrict__ out,
    int B)
{
    const int tid = blockIdx.x * blockDim.x + threadIdx.x;

    // times = linspace(0,100,101): exact small integers in f32
    if (tid < NSAVE) out[(size_t)B * 222 + tid] = (float)tid;
    if (tid >= B) return;

    const float iptg_max = params[0];
    const float K        = params[1];
    const float n_iptg   = params[2];
    const float a1       = params[3];
    const float a2       = params[4];
    const float n_ab     = params[5];
    const float n_ba     = params[6];

    const int p = tid;
    const float* ub = useq + (size_t)p * (NCTRL * 2);

    // u clip+copy: 20 floats per trajectory, 16B aligned
    {
        float* dst = out + (size_t)B * 202 + (size_t)p * (NCTRL * 2);
        #pragma unroll
        for (int i = 0; i < 5; ++i) {
            float4 v = reinterpret_cast<const float4*>(ub)[i];
            v.x = fminf(fmaxf(v.x, 0.0f), 1.0f);
            v.y = fminf(fmaxf(v.y, 0.0f), 1.0f);
            v.z = fminf(fmaxf(v.z, 0.0f), 1.0f);
            v.w = fminf(fmaxf(v.w, 0.0f), 1.0f);
            reinterpret_cast<float4*>(dst)[i] = v;
        }
    }

    const bool special = (n_iptg == 2.0f) && (n_ab == 2.5f) && (n_ba == 1.0f);

    float* ys = out + (size_t)p * 202;
    int bad = 0;

    if (special) {
        // ---- packed q-form, state s = {pA, zB} with pA = 1 + zA.
        //      p-coords make the A-side rcp operand the stage fma output
        //      directly; per-stage shared-rcp computes both reciprocals
        //      from ONE v_rcp: m=rcp(pA*qB); rA=pA*m; rB=qB*m.
        //      -> 12 trans/substep (6 sqrt + 6 rcp) vs R8's 18. ----
        float xA0 = init[(size_t)p * 2 + 0];
        float xB0 = init[(size_t)p * 2 + 1];
        {
            float wA = xA0, wB = xB0;
            if (!__builtin_isfinite(wA)) { wA = 0.0f; ++bad; }
            if (!__builtin_isfinite(wB)) { wB = 0.0f; ++bad; }
            *reinterpret_cast<float2*>(&ys[0]) = make_float2(wA, wB);
        }

        auto mk_den = [&](int k, int c) -> float {
            float u  = fminf(fmaxf(ub[k * 2 + c], 0.0f), 1.0f);
            float xx = (u * iptg_max) / K;
            return 1.0f + xx * xx;
        };

        float denA = mk_den(0, 0), denB = mk_den(0, 1);
        float rdA = 1.0f / denA,  rdB = 1.0f / denB;
        v2f s = { 1.0f + xA0 * rdA, xB0 * rdB };

        // broadcast coefficient pairs (compile-time values)
        const v2f nHA21 = {-HA21, -HA21};
        const v2f nHA31 = {-HA31, -HA31}, nHA32 = {-HA32, -HA32};
        const v2f nHA41 = {-HA41, -HA41}, nHA42 = {-HA42, -HA42}, nHA43 = {-HA43, -HA43};
        const v2f nHA51 = {-HA51, -HA51}, nHA52 = {-HA52, -HA52}, nHA53 = {-HA53, -HA53}, nHA54 = {-HA54, -HA54};
        const v2f nHA61 = {-HA61, -HA61}, nHA62 = {-HA62, -HA62}, nHA63 = {-HA63, -HA63}, nHA64 = {-HA64, -HA64}, nHA65 = {-HA65, -HA65};
        const v2f nHB1 = {-HB1, -HB1}, nHB2 = {-HB2, -HB2}, nHB3 = {-HB3, -HB3};
        const v2f nHB4 = {-HB4, -HB4}, nHB5 = {-HB5, -HB5}, nHB6 = {-HB6, -HB6};

        // per-group coefficient pairs: AN_ij = {HA_ij*a1*rdA, HA_ij*a2*rdB}
        v2f AN21, AN31, AN32, AN41, AN42, AN43, AN51, AN52, AN53, AN54,
            AN61, AN62, AN63, AN64, AN65, BN1, BN2, BN3, BN4, BN5, BN6;
        auto rebuild = [&](float RNA, float RNB) {
            AN21 = (v2f){HA21 * RNA, HA21 * RNB};
            AN31 = (v2f){HA31 * RNA, HA31 * RNB}; AN32 = (v2f){HA32 * RNA, HA32 * RNB};
            AN41 = (v2f){HA41 * RNA, HA41 * RNB}; AN42 = (v2f){HA42 * RNA, HA42 * RNB}; AN43 = (v2f){HA43 * RNA, HA43 * RNB};
            AN51 = (v2f){HA51 * RNA, HA51 * RNB}; AN52 = (v2f){HA52 * RNA, HA52 * RNB}; AN53 = (v2f){HA53 * RNA, HA53 * RNB}; AN54 = (v2f){HA54 * RNA, HA54 * RNB};
            AN61 = (v2f){HA61 * RNA, HA61 * RNB}; AN62 = (v2f){HA62 * RNA, HA62 * RNB}; AN63 = (v2f){HA63 * RNA, HA63 * RNB}; AN64 = (v2f){HA64 * RNA, HA64 * RNB}; AN65 = (v2f){HA65 * RNA, HA65 * RNB};
            BN1 = (v2f){HB1 * RNA, HB1 * RNB}; BN2 = (v2f){HB2 * RNA, HB2 * RNB}; BN3 = (v2f){HB3 * RNA, HB3 * RNB};
            BN4 = (v2f){HB4 * RNA, HB4 * RNB}; BN5 = (v2f){HB5 * RNA, HB5 * RNB}; BN6 = (v2f){HB6 * RNA, HB6 * RNB};
        };
        rebuild(a1 * rdA, a2 * rdB);

        // shared-rcp export: si = {pA, zB}.
        // qB = 1 + zB^2.5 (fma-fused); m = rcp(pA*qB);
        // r = {rA, rB} = {pA*m, qB*m} = {1/qB, 1/pA} (to ~2ulp).
        auto stage_r = [&](v2f si) -> v2f {
            float zb = si.y;
            float qB = __builtin_fmaf(zb * zb, __builtin_amdgcn_sqrtf(zb), 1.0f);
            float m  = __builtin_amdgcn_rcpf(si.x * qB);
            v2f pq = { si.x, qB };
            v2f mm = { m, m };
            return pq * mm;   // v_pk_mul_f32
        };

        auto substep = [&](auto s6tag, v2f s6mul, v2f s6add) {
            v2f s1 = s;
            v2f r1 = stage_r(s1);

            v2f b2 = pk_fma(nHA21, s1, s1 + (v2f){K2, 0.0f});
            v2f s2 = pk_fma(AN21, r1, b2);
            v2f r2 = stage_r(s2);

            v2f b3 = pk_fma(nHA31, s1, s1 + (v2f){K3, 0.0f});
            b3 = pk_fma(AN31, r1, b3);
            b3 = pk_fma(nHA32, s2, b3);
            v2f s3 = pk_fma(AN32, r2, b3);
            v2f r3 = stage_r(s3);

            v2f b4 = pk_fma(nHA41, s1, s1 + (v2f){K4, 0.0f});
            b4 = pk_fma(AN41, r1, b4);
            b4 = pk_fma(nHA42, s2, b4);
            b4 = pk_fma(AN42, r2, b4);
            b4 = pk_fma(nHA43, s3, b4);
            v2f s4 = pk_fma(AN43, r3, b4);
            v2f r4 = stage_r(s4);

            v2f b5 = pk_fma(nHA51, s1, s1 + (v2f){K5, 0.0f});
            b5 = pk_fma(AN51, r1, b5);
            b5 = pk_fma(nHA52, s2, b5);
            b5 = pk_fma(AN52, r2, b5);
            b5 = pk_fma(nHA53, s3, b5);
            b5 = pk_fma(AN53, r3, b5);
            b5 = pk_fma(nHA54, s4, b5);
            v2f s5 = pk_fma(AN54, r4, b5);
            v2f r5 = stage_r(s5);

            v2f b6 = pk_fma(nHA61, s1, s1 + (v2f){K6, 0.0f});
            b6 = pk_fma(AN61, r1, b6);
            b6 = pk_fma(nHA62, s2, b6);
            b6 = pk_fma(AN62, r2, b6);
            b6 = pk_fma(nHA63, s3, b6);
            b6 = pk_fma(AN63, r3, b6);
            b6 = pk_fma(nHA64, s4, b6);
            b6 = pk_fma(AN64, r4, b6);
            b6 = pk_fma(nHA65, s5, b6);
            v2f s6v = pk_fma(AN65, r5, b6);

            v2f w6 = s6v;
            if constexpr (decltype(s6tag)::value) w6 = pk_fma(s6mul, s6v, s6add);
            v2f r6 = stage_r(w6);

            v2f by = pk_fma(nHB1, s1, s1 + (v2f){KY, 0.0f});
            by = pk_fma(BN1, r1, by);
            by = pk_fma(nHB2, s2, by);
            by = pk_fma(BN2, r2, by);
            by = pk_fma(nHB3, s3, by);
            by = pk_fma(BN3, r3, by);
            by = pk_fma(nHB4, s4, by);
            by = pk_fma(BN4, r4, by);
            by = pk_fma(nHB5, s5, by);
            by = pk_fma(BN5, r5, by);
            by = pk_fma(nHB6, s6v, by);
            s = pk_fma(BN6, r6, by);
        };

        #pragma unroll 1
        for (int k = 0; k < NCTRL; ++k) {
            const int kn = (k < NCTRL - 1) ? (k + 1) : k;
            const float denA_nx = mk_den(kn, 0), denB_nx = mk_den(kn, 1);
            const float rdA_nx = 1.0f / denA_nx, rdB_nx = 1.0f / denB_nx;
            const float ratioA = (kn != k) ? (denA * rdA_nx) : 1.0f;
            const float ratioB = (kn != k) ? (denB * rdB_nx) : 1.0f;
            const float cA = 1.0f - ratioA;   // pA' = ratioA*pA + (1-ratioA)
            const float bnd = 10.0f * (float)(k + 1);

            #pragma unroll 1
            for (int iv2 = 0; iv2 < IV_PER_K; ++iv2) {
                const int iv = k * IV_PER_K + iv2;
                float t = (float)iv;   // exact

                #pragma unroll 1
                for (int j = 0; j < NSUB - 1; ++j) {
                    substep(std::integral_constant<bool, false>{},
                            (v2f){1.0f, 1.0f}, (v2f){0.0f, 0.0f});
                    t = t + 0.05f;     // bit-exact reference t accumulation
                }
                // peeled substep 19: stage-6 may cross the control boundary.
                // A-half (p-coords): pA6' = ratioA*pA6 + (1-ratioA);
                // B-half (z-coords): zB6' = ratioB*zB6. fma(1,x,0)=x exact.
                {
                    bool cross = (iv2 == IV_PER_K - 1) && (t + 0.05f >= bnd);
                    v2f s6mul = cross ? (v2f){ratioA, ratioB} : (v2f){1.0f, 1.0f};
                    v2f s6add = cross ? (v2f){cA, 0.0f} : (v2f){0.0f, 0.0f};
                    substep(std::integral_constant<bool, true>{}, s6mul, s6add);
                }

                // unscale: xA = (pA-1)*denA = pA*denA - denA ; xB = zB*denB
                float wA = __builtin_fmaf(s.x, denA, -denA);
                float wB = s.y * denB;
                if (!__builtin_isfinite(wA)) { wA = 0.0f; ++bad; }
                if (!__builtin_isfinite(wB)) { wB = 0.0f; ++bad; }
                *reinterpret_cast<float2*>(&ys[(size_t)(iv + 1) * 2]) = make_float2(wA, wB);
            }

            // enter next group's coordinates
            s = pk_fma((v2f){ratioA, ratioB}, s, (v2f){cA, 0.0f});
            denA = denA_nx; rdA = rdA_nx;
            denB = denB_nx; rdB = rdB_nx;
            rebuild(a1 * rdA, a2 * rdB);
        }

    } else {
        // ---- generic fallback: straightforward, IEEE ----
        float A  = init[(size_t)p * 2 + 0];
        float Bc = init[(size_t)p * 2 + 1];
        {
            float wA = A, wB = Bc;
            if (!__builtin_isfinite(wA)) { wA = 0.0f; ++bad; }
            if (!__builtin_isfinite(wB)) { wB = 0.0f; ++bad; }
            ys[0] = wA; ys[1] = wB;
        }

        const float h = 0.05f;
        const float A21f = 0.161f;
        const float A31f = -0.008480655492356989f, A32f = 0.335480655492357f;
        const float A41f = 2.8971530571054935f,  A42f = -6.359448489975075f,  A43f = 4.3622954328695815f;
        const float A51f = 5.325864828439257f,   A52f = -11.748883564062828f, A53f = 7.4955393428898365f, A54f = -0.09249506636175525f;
        const float A61f = 5.86145544294642f,    A62f = -12.92096931784711f,  A63f = 8.159367898576159f,  A64f = -0.071584973281401f, A65f = -0.028269050394068383f;
        const float B1f = 0.09646076681806523f, B2f = 0.01f, B3f = 0.4798896504144996f;
        const float B4f = 1.379008574103742f,   B5f = -3.290069515436081f, B6f = 2.324710524099774f;

        auto mk_den = [&](int k, float& dA_, float& dB_) {
            float u0 = fminf(fmaxf(ub[k * 2 + 0], 0.0f), 1.0f);
            float u1 = fminf(fmaxf(ub[k * 2 + 1], 0.0f), 1.0f);
            float xA = (u0 * iptg_max) / K;
            float xB = (u1 * iptg_max) / K;
            dA_ = 1.0f + pow_np_f32(xA, n_iptg);
            dB_ = 1.0f + pow_np_f32(xB, n_iptg);
        };
        auto vf = [&](float rdA, float rdB, float As, float Bs, float& dA, float& dB) {
            float A_eff = As * rdA;
            float B_eff = Bs * rdB;
            float pB = pow_np_f32(B_eff, n_ab);
            float pA = pow_np_f32(A_eff, n_ba);
            dA = a1 / (1.0f + pB) - As;
            dB = a2 / (1.0f + pA) - Bs;
        };

        float denA, denB;
        mk_den(0, denA, denB);
        float rdenA = 1.0f / denA, rdenB = 1.0f / denB;

        #pragma unroll 1
        for (int k = 0; k < NCTRL; ++k) {
            int kn = (k < NCTRL - 1) ? (k + 1) : k;
            float denA_nx, denB_nx;
            mk_den(kn, denA_nx, denB_nx);
            float rdenA_nx = 1.0f / denA_nx, rdenB_nx = 1.0f / denB_nx;
            const float bnd = 10.0f * (float)(k + 1);

            #pragma unroll 1
            for (int iv2 = 0; iv2 < IV_PER_K; ++iv2) {
                const int iv = k * IV_PER_K + iv2;
                float t = (float)iv;
                #pragma unroll 1
                for (int j = 0; j < NSUB; ++j) {
                    bool nx = (iv2 == IV_PER_K - 1) && (j == NSUB - 1) && (t + 0.05f >= bnd);
                    float rdA6 = nx ? rdenA_nx : rdenA;
                    float rdB6 = nx ? rdenB_nx : rdenB;

                    float k1A, k1B, k2A, k2B, k3A, k3B, k4A, k4B, k5A, k5B, k6A, k6B;
                    vf(rdenA, rdenB, A, Bc, k1A, k1B);
                    vf(rdenA, rdenB, A + h * (A21f * k1A), Bc + h * (A21f * k1B), k2A, k2B);
                    vf(rdenA, rdenB, A + h * (A31f * k1A + A32f * k2A), Bc + h * (A31f * k1B + A32f * k2B), k3A, k3B);
                    vf(rdenA, rdenB, A + h * (A41f * k1A + A42f * k2A + A43f * k3A),
                                      Bc + h * (A41f * k1B + A42f * k2B + A43f * k3B), k4A, k4B);
                    vf(rdenA, rdenB, A + h * (A51f * k1A + A52f * k2A + A53f * k3A + A54f * k4A),
                                      Bc + h * (A51f * k1B + A52f * k2B + A53f * k3B + A54f * k4B), k5A, k5B);
                    vf(rdA6, rdB6,   A + h * (A61f * k1A + A62f * k2A + A63f * k3A + A64f * k4A + A65f * k5A),
                                      Bc + h * (A61f * k1B + A62f * k2B + A63f * k3B + A64f * k4B + A65f * k5B), k6A, k6B);

                    A  = A  + h * (B1f * k1A + B2f * k2A + B3f * k3A + B4f * k4A + B5f * k5A + B6f * k6A);
                    Bc = Bc + h * (B1f * k1B + B2f * k2B + B3f * k3B + B4f * k4B + B5f * k5B + B6f * k6B);
                    t  = t + h;
                }
                float wA = A, wB = Bc;
                if (!__builtin_isfinite(wA)) { wA = 0.0f; ++bad; }
                if (!__builtin_isfinite(wB)) { wB = 0.0f; ++bad; }
                ys[(size_t)(iv + 1) * 2 + 0] = wA;
                ys[(size_t)(iv + 1) * 2 + 1] = wB;
            }
            denA = denA_nx; denB = denB_nx;
            rdenA = rdenA_nx; rdenB = rdenB_nx;
        }
    }

    if (bad) atomicAdd(out + (size_t)B * 222 + NSAVE, (float)bad);
}

extern "C" void kernel_launch(void* const* d_in, const int* in_sizes, int n_in,
                              void* d_out, int out_size, void* d_ws, size_t ws_size,
                              hipStream_t stream) {
    const float* init   = (const float*)d_in[0];
    const float* useq   = (const float*)d_in[1];
    const float* params = (const float*)d_in[2];
    float* out = (float*)d_out;

    const int B = in_sizes[0] / 2;

    // zero the n_bad accumulator slot (graph-capture-safe async memset)
    hipMemsetAsync(out + (size_t)B * 222 + NSAVE, 0, sizeof(float), stream);

    const int block = 256;
    const int grid  = (B + block - 1) / block;
    hipLaunchKernelGGL(toggle_tsit5_kernel, dim3(grid), dim3(block), 0, stream,
                       init, useq, params, out, B);
}

// Round 10
// 356.677 us; speedup vs baseline: 1.1815x; 1.1815x over previous
//
#include <hip/hip_runtime.h>
#include <cmath>
#include <type_traits>

#pragma clang fp contract(off)

#define NSAVE 101
#define NSUB  20
#define NCTRL 10
#define IV_PER_K 10   // 100 save intervals / 10 control intervals

typedef float v2f __attribute__((ext_vector_type(2)));

// Packed f32 fma via llvm.fma.v2f32 -> v_pk_fma_f32 (per-element IEEE,
// R8-verified bit-stable). Used ONLY for off-critical-chain bracket work;
// chain-critical ops are scalar so the fast (B) parity never waits on the
// slow (A/sqrt) parity.
__device__ __forceinline__ v2f pk_fma(v2f a, v2f b, v2f c) {
    return __builtin_elementwise_fma(a, b, c);
}

// np-faithful pow for the exponents that occur (generic fallback path only).
__device__ __forceinline__ float pow_np_f32(float x, float p) {
    if (p == 2.5f) return (x * x) * sqrtf(x);
    if (p == 1.0f) return x;
    if (p == 2.0f) return x * x;
    return powf(x, p);
}

// h-premultiplied Butcher constants (double product, rounded once)
#define HCF(x) ((float)(0.05 * (x)))
__device__ constexpr float HA21 = HCF(0.161);
__device__ constexpr float HA31 = HCF(-0.008480655492356989), HA32 = HCF(0.335480655492357);
__device__ constexpr float HA41 = HCF(2.8971530571054935),  HA42 = HCF(-6.359448489975075),  HA43 = HCF(4.3622954328695815);
__device__ constexpr float HA51 = HCF(5.325864828439257),   HA52 = HCF(-11.748883564062828), HA53 = HCF(7.4955393428898365), HA54 = HCF(-0.09249506636175525);
__device__ constexpr float HA61 = HCF(5.86145544294642),    HA62 = HCF(-12.92096931784711),  HA63 = HCF(8.159367898576159),  HA64 = HCF(-0.071584973281401), HA65 = HCF(-0.028269050394068383);
__device__ constexpr float HB1 = HCF(0.09646076681806523), HB2 = HCF(0.01), HB3 = HCF(0.4798896504144996);
__device__ constexpr float HB4 = HCF(1.379008574103742),   HB5 = HCF(-3.290069515436081), HB6 = HCF(2.324710524099774);

__global__ __launch_bounds__(256, 1) void toggle_tsit5_kernel(
    const float* __restrict__ init,
    const float* __restrict__ useq,
    const float* __restrict__ params,
    float* __restrict__ out,
    int B)
{
    const int tid = blockIdx.x * blockDim.x + threadIdx.x;

    // times = linspace(0,100,101): exact small integers in f32
    if (tid < NSAVE) out[(size_t)B * 222 + tid] = (float)tid;
    if (tid >= B) return;

    const float iptg_max = params[0];
    const float K        = params[1];
    const float n_iptg   = params[2];
    const float a1       = params[3];
    const float a2       = params[4];
    const float n_ab     = params[5];
    const float n_ba     = params[6];

    const int p = tid;
    const float* ub = useq + (size_t)p * (NCTRL * 2);

    // u clip+copy: 20 floats per trajectory, 16B aligned
    {
        float* dst = out + (size_t)B * 202 + (size_t)p * (NCTRL * 2);
        #pragma unroll
        for (int i = 0; i < 5; ++i) {
            float4 v = reinterpret_cast<const float4*>(ub)[i];
            v.x = fminf(fmaxf(v.x, 0.0f), 1.0f);
            v.y = fminf(fmaxf(v.y, 0.0f), 1.0f);
            v.z = fminf(fmaxf(v.z, 0.0f), 1.0f);
            v.w = fminf(fmaxf(v.w, 0.0f), 1.0f);
            reinterpret_cast<float4*>(dst)[i] = v;
        }
    }

    const bool special = (n_iptg == 2.0f) && (n_ab == 2.5f) && (n_ba == 1.0f);

    float* ys = out + (size_t)p * 202;
    int bad = 0;

    if (special) {
        // ---- parity-decoupled q-form: state (zx=A-half, zy=B-half) scalar.
        //      Chain: zx_{i+1} <- rA_i <- sqrt-chain(zy_i)  [L]
        //             zy_{i+1} <- rB_i <- add+rcp(zx_i)     [S]
        //      Scalar tails keep L and S independent (3L+3S per substep);
        //      bracket accumulations (kh/c) are packed pk_fma (off-chain). ----
        float xA0 = init[(size_t)p * 2 + 0];
        float xB0 = init[(size_t)p * 2 + 1];
        {
            float wA = xA0, wB = xB0;
            if (!__builtin_isfinite(wA)) { wA = 0.0f; ++bad; }
            if (!__builtin_isfinite(wB)) { wB = 0.0f; ++bad; }
            *reinterpret_cast<float2*>(&ys[0]) = make_float2(wA, wB);
        }

        auto mk_den = [&](int k, int c) -> float {
            float u  = fminf(fmaxf(ub[k * 2 + c], 0.0f), 1.0f);
            float xx = (u * iptg_max) / K;
            return 1.0f + xx * xx;
        };

        float denA = mk_den(0, 0), denB = mk_den(0, 1);
        float rdA = 1.0f / denA,  rdB = 1.0f / denB;
        float zx = xA0 * rdA, zy = xB0 * rdB;

        // compile-time packed broadcasts for bracket (kh/c) accumulation
        const v2f nHA31v = {-HA31, -HA31};
        const v2f nHA41v = {-HA41, -HA41}, nHA42v = {-HA42, -HA42};
        const v2f nHA51v = {-HA51, -HA51}, nHA52v = {-HA52, -HA52}, nHA53v = {-HA53, -HA53};
        const v2f nHA61v = {-HA61, -HA61}, nHA62v = {-HA62, -HA62}, nHA63v = {-HA63, -HA63}, nHA64v = {-HA64, -HA64};
        const v2f nHB1v = {-HB1, -HB1}, nHB2v = {-HB2, -HB2}, nHB3v = {-HB3, -HB3}, nHB4v = {-HB4, -HB4}, nHB5v = {-HB5, -HB5};

        // per-group runtime scalars (chain tails) + packed nRN (kh)
        float RNA, RNB;
        v2f nRN;
        float ANA21, ANB21, ANA32, ANB32, ANA43, ANB43, ANA54, ANB54, ANA65, ANB65, BNA6, BNB6;
        auto rebuild = [&](float rna, float rnb) {
            RNA = rna; RNB = rnb;
            nRN = (v2f){-rna, -rnb};
            ANA21 = HA21 * rna; ANB21 = HA21 * rnb;
            ANA32 = HA32 * rna; ANB32 = HA32 * rnb;
            ANA43 = HA43 * rna; ANB43 = HA43 * rnb;
            ANA54 = HA54 * rna; ANB54 = HA54 * rnb;
            ANA65 = HA65 * rna; ANB65 = HA65 * rnb;
            BNA6  = HB6  * rna; BNB6  = HB6  * rnb;
        };
        rebuild(a1 * rdA, a2 * rdB);

        // scalar exports — bit-identical to R8's stage_r halves:
        // rA = rcp(1 + zy^2.5) (feeds A/x-half), rB = rcp(zx + 1) (feeds B/y-half)
        auto expA = [](float zyv) -> float {
            float q = __builtin_fmaf(zyv * zyv, __builtin_amdgcn_sqrtf(zyv), 1.0f);
            return __builtin_amdgcn_rcpf(q);
        };
        auto expB = [](float zxv) -> float {
            return __builtin_amdgcn_rcpf(zxv + 1.0f);
        };

        auto substep = [&](auto s6tag, float s6A, float s6B) {
            const float zx1 = zx, zy1 = zy;
            float rA1 = expA(zy1);
            float rB1 = expB(zx1);
            v2f z1v = {zx1, zy1};
            v2f kh1 = pk_fma(nRN, (v2f){rA1, rB1}, z1v);   // kh = z - RN*r

            // stage 2 (c2 = z1; expanded tail, scalar per parity)
            float by2 = __builtin_fmaf(-HA21, zy1, zy1);
            float zy2 = __builtin_fmaf(ANB21, rB1, by2);
            float rA2 = expA(zy2);
            float bx2 = __builtin_fmaf(-HA21, zx1, zx1);
            float zx2 = __builtin_fmaf(ANA21, rA1, bx2);
            float rB2 = expB(zx2);
            v2f kh2 = pk_fma(nRN, (v2f){rA2, rB2}, (v2f){zx2, zy2});

            // stage 3
            v2f c3 = pk_fma(nHA31v, kh1, z1v);
            float by3 = __builtin_fmaf(-HA32, zy2, c3.y);
            float zy3 = __builtin_fmaf(ANB32, rB2, by3);
            float rA3 = expA(zy3);
            float bx3 = __builtin_fmaf(-HA32, zx2, c3.x);
            float zx3 = __builtin_fmaf(ANA32, rA2, bx3);
            float rB3 = expB(zx3);
            v2f kh3 = pk_fma(nRN, (v2f){rA3, rB3}, (v2f){zx3, zy3});

            // stage 4
            v2f c4 = pk_fma(nHA42v, kh2, pk_fma(nHA41v, kh1, z1v));
            float by4 = __builtin_fmaf(-HA43, zy3, c4.y);
            float zy4 = __builtin_fmaf(ANB43, rB3, by4);
            float rA4 = expA(zy4);
            float bx4 = __builtin_fmaf(-HA43, zx3, c4.x);
            float zx4 = __builtin_fmaf(ANA43, rA3, bx4);
            float rB4 = expB(zx4);
            v2f kh4 = pk_fma(nRN, (v2f){rA4, rB4}, (v2f){zx4, zy4});

            // stage 5
            v2f c5 = pk_fma(nHA53v, kh3, pk_fma(nHA52v, kh2, pk_fma(nHA51v, kh1, z1v)));
            float by5 = __builtin_fmaf(-HA54, zy4, c5.y);
            float zy5 = __builtin_fmaf(ANB54, rB4, by5);
            float rA5 = expA(zy5);
            float bx5 = __builtin_fmaf(-HA54, zx4, c5.x);
            float zx5 = __builtin_fmaf(ANA54, rA4, bx5);
            float rB5 = expB(zx5);
            v2f kh5 = pk_fma(nRN, (v2f){rA5, rB5}, (v2f){zx5, zy5});

            // stage 6
            v2f c6 = pk_fma(nHA64v, kh4, pk_fma(nHA63v, kh3, pk_fma(nHA62v, kh2, pk_fma(nHA61v, kh1, z1v))));
            float by6 = __builtin_fmaf(-HA65, zy5, c6.y);
            float zy6 = __builtin_fmaf(ANB65, rB5, by6);
            float bx6 = __builtin_fmaf(-HA65, zx5, c6.x);
            float zx6 = __builtin_fmaf(ANA65, rA5, bx6);

            // stage-6 control-boundary scale (peeled substep only)
            float w6x, w6y;
            if constexpr (decltype(s6tag)::value) { w6x = zx6 * s6A; w6y = zy6 * s6B; }
            else { (void)s6A; (void)s6B; w6x = zx6; w6y = zy6; }
            float rA6 = expA(w6y);
            float rB6 = expB(w6x);

            // y-update row: cy = z1 - sum_{j=1..5} HB_j*kh_j ; j=6 expanded
            v2f cy = pk_fma(nHB5v, kh5,
                     pk_fma(nHB4v, kh4,
                     pk_fma(nHB3v, kh3,
                     pk_fma(nHB2v, kh2,
                     pk_fma(nHB1v, kh1, z1v)))));
            float byy = __builtin_fmaf(-HB6, zy6, cy.y);
            zy = __builtin_fmaf(BNB6, rB6, byy);
            float byx = __builtin_fmaf(-HB6, zx6, cy.x);
            zx = __builtin_fmaf(BNA6, rA6, byx);
        };

        #pragma unroll 1
        for (int k = 0; k < NCTRL; ++k) {
            const int kn = (k < NCTRL - 1) ? (k + 1) : k;
            const float denA_nx = mk_den(kn, 0), denB_nx = mk_den(kn, 1);
            const float rdA_nx = 1.0f / denA_nx, rdB_nx = 1.0f / denB_nx;
            const float ratioA = (kn != k) ? (denA * rdA_nx) : 1.0f;
            const float ratioB = (kn != k) ? (denB * rdB_nx) : 1.0f;
            const float bnd = 10.0f * (float)(k + 1);

            // data-independent boundary-crossing flag for this group's last
            // interval: exact replica of the reference's f32 t-accumulation
            // (t0 = (float)(k*10+9), 19 x +0.05f, test t+0.05f >= bnd).
            bool cross_k;
            {
                float tt = (float)(k * 10 + 9);
                #pragma unroll 1
                for (int j = 0; j < NSUB - 1; ++j) tt = tt + 0.05f;
                cross_k = (tt + 0.05f >= bnd);
            }

            #pragma unroll 1
            for (int iv2 = 0; iv2 < IV_PER_K; ++iv2) {
                const int iv = k * IV_PER_K + iv2;

                #pragma unroll 1
                for (int j = 0; j < NSUB - 1; ++j) {
                    substep(std::integral_constant<bool, false>{}, 1.0f, 1.0f);
                }
                // peeled substep 19: stage-6 may cross the control boundary
                {
                    bool cross = (iv2 == IV_PER_K - 1) && cross_k;
                    float s6A = cross ? ratioA : 1.0f;
                    float s6B = cross ? ratioB : 1.0f;
                    substep(std::integral_constant<bool, true>{}, s6A, s6B);
                }

                float wA = zx * denA, wB = zy * denB;
                if (!__builtin_isfinite(wA)) { wA = 0.0f; ++bad; }
                if (!__builtin_isfinite(wB)) { wB = 0.0f; ++bad; }
                *reinterpret_cast<float2*>(&ys[(size_t)(iv + 1) * 2]) = make_float2(wA, wB);
            }

            // enter next group's scaled coordinates
            zx = zx * ratioA;
            zy = zy * ratioB;
            denA = denA_nx; rdA = rdA_nx;
            denB = denB_nx; rdB = rdB_nx;
            rebuild(a1 * rdA, a2 * rdB);
        }

    } else {
        // ---- generic fallback: straightforward, IEEE ----
        float A  = init[(size_t)p * 2 + 0];
        float Bc = init[(size_t)p * 2 + 1];
        {
            float wA = A, wB = Bc;
            if (!__builtin_isfinite(wA)) { wA = 0.0f; ++bad; }
            if (!__builtin_isfinite(wB)) { wB = 0.0f; ++bad; }
            ys[0] = wA; ys[1] = wB;
        }

        const float h = 0.05f;
        const float A21f = 0.161f;
        const float A31f = -0.008480655492356989f, A32f = 0.335480655492357f;
        const float A41f = 2.8971530571054935f,  A42f = -6.359448489975075f,  A43f = 4.3622954328695815f;
        const float A51f = 5.325864828439257f,   A52f = -11.748883564062828f, A53f = 7.4955393428898365f, A54f = -0.09249506636175525f;
        const float A61f = 5.86145544294642f,    A62f = -12.92096931784711f,  A63f = 8.159367898576159f,  A64f = -0.071584973281401f, A65f = -0.028269050394068383f;
        const float B1f = 0.09646076681806523f, B2f = 0.01f, B3f = 0.4798896504144996f;
        const float B4f = 1.379008574103742f,   B5f = -3.290069515436081f, B6f = 2.324710524099774f;

        auto mk_den = [&](int k, float& dA_, float& dB_) {
            float u0 = fminf(fmaxf(ub[k * 2 + 0], 0.0f), 1.0f);
            float u1 = fminf(fmaxf(ub[k * 2 + 1], 0.0f), 1.0f);
            float xA = (u0 * iptg_max) / K;
            float xB = (u1 * iptg_max) / K;
            dA_ = 1.0f + pow_np_f32(xA, n_iptg);
            dB_ = 1.0f + pow_np_f32(xB, n_iptg);
        };
        auto vf = [&](float rdA_, float rdB_, float As, float Bs, float& dA, float& dB) {
            float A_eff = As * rdA_;
            float B_eff = Bs * rdB_;
            float pB = pow_np_f32(B_eff, n_ab);
            float pA = pow_np_f32(A_eff, n_ba);
            dA = a1 / (1.0f + pB) - As;
            dB = a2 / (1.0f + pA) - Bs;
        };

        float denA, denB;
        mk_den(0, denA, denB);
        float rdenA = 1.0f / denA, rdenB = 1.0f / denB;

        #pragma unroll 1
        for (int k = 0; k < NCTRL; ++k) {
            int kn = (k < NCTRL - 1) ? (k + 1) : k;
            float denA_nx, denB_nx;
            mk_den(kn, denA_nx, denB_nx);
            float rdenA_nx = 1.0f / denA_nx, rdenB_nx = 1.0f / denB_nx;
            const float bnd = 10.0f * (float)(k + 1);

            #pragma unroll 1
            for (int iv2 = 0; iv2 < IV_PER_K; ++iv2) {
                const int iv = k * IV_PER_K + iv2;
                float t = (float)iv;
                #pragma unroll 1
                for (int j = 0; j < NSUB; ++j) {
                    bool nx = (iv2 == IV_PER_K - 1) && (j == NSUB - 1) && (t + 0.05f >= bnd);
                    float rdA6 = nx ? rdenA_nx : rdenA;
                    float rdB6 = nx ? rdenB_nx : rdenB;

                    float k1A, k1B, k2A, k2B, k3A, k3B, k4A, k4B, k5A, k5B, k6A, k6B;
                    vf(rdenA, rdenB, A, Bc, k1A, k1B);
                    vf(rdenA, rdenB, A + h * (A21f * k1A), Bc + h * (A21f * k1B), k2A, k2B);
                    vf(rdenA, rdenB, A + h * (A31f * k1A + A32f * k2A), Bc + h * (A31f * k1B + A32f * k2B), k3A, k3B);
                    vf(rdenA, rdenB, A + h * (A41f * k1A + A42f * k2A + A43f * k3A),
                                      Bc + h * (A41f * k1B + A42f * k2B + A43f * k3B), k4A, k4B);
                    vf(rdenA, rdenB, A + h * (A51f * k1A + A52f * k2A + A53f * k3A + A54f * k4A),
                                      Bc + h * (A51f * k1B + A52f * k2B + A53f * k3B + A54f * k4B), k5A, k5B);
                    vf(rdA6, rdB6,   A + h * (A61f * k1A + A62f * k2A + A63f * k3A + A64f * k4A + A65f * k5A),
                                      Bc + h * (A61f * k1B + A62f * k2B + A63f * k3B + A64f * k4B + A65f * k5B), k6A, k6B);

                    A  = A  + h * (B1f * k1A + B2f * k2A + B3f * k3A + B4f * k4A + B5f * k5A + B6f * k6A);
                    Bc = Bc + h * (B1f * k1B + B2f * k2B + B3f * k3B + B4f * k4B + B5f * k5B + B6f * k6B);
                    t  = t + h;
                }
                float wA = A, wB = Bc;
                if (!__builtin_isfinite(wA)) { wA = 0.0f; ++bad; }
                if (!__builtin_isfinite(wB)) { wB = 0.0f; ++bad; }
                ys[(size_t)(iv + 1) * 2 + 0] = wA;
                ys[(size_t)(iv + 1) * 2 + 1] = wB;
            }
            denA = denA_nx; denB = denB_nx;
            rdenA = rdenA_nx; rdenB = rdenB_nx;
        }
    }

    if (bad) atomicAdd(out + (size_t)B * 222 + NSAVE, (float)bad);
}

extern "C" void kernel_launch(void* const* d_in, const int* in_sizes, int n_in,
                              void* d_out, int out_size, void* d_ws, size_t ws_size,
                              hipStream_t stream) {
    const float* init   = (const float*)d_in[0];
    const float* useq   = (const float*)d_in[1];
    const float* params = (const float*)d_in[2];
    float* out = (float*)d_out;

    const int B = in_sizes[0] / 2;

    // zero the n_bad accumulator slot (graph-capture-safe async memset)
    hipMemsetAsync(out + (size_t)B * 222 + NSAVE, 0, sizeof(float), stream);

    const int block = 256;
    const int grid  = (B + block - 1) / block;
    hipLaunchKernelGGL(toggle_tsit5_kernel, dim3(grid), dim3(block), 0, stream,
                       init, useq, params, out, B);
}